// Round 3
// baseline (5922.524 us; speedup 1.0000x reference)
//
#include <hip/hip_runtime.h>
#include <math.h>

// POSTagEncoder: expert-routed linear -> 1-layer LSTM (i,f,g,o) -> time max-pool.
// S=8192, D=128, E=48. Output [1,128] fp32.
//
// K2 lstm_scan (the 97% kernel): 1 block, 256 threads (4 waves, 2 gate-rows per
// thread). W_hh held as packed half2 in registers. Round-2 lesson: VGPR_Count=100
// proved the weight arrays went to scratch (rolled loop -> dynamic index -> no
// SROA). This version MACRO-EXPANDS the weight load and the dot loop so every
// array index and readlane lane is a compile-time constant, and caps the register
// budget at 256 via __launch_bounds__(256,2) (need ~165 -> pure arch VGPRs).

#define SEQ   8192
#define DIM   128
#define NGATE 512
#define NEXP  48

typedef _Float16 half2v __attribute__((ext_vector_type(2)));

__device__ __forceinline__ float sigm_fast(float x) {
    return __fdividef(1.0f, 1.0f + __expf(-x));   // inf-safe both ends
}
__device__ __forceinline__ float tanh_fast(float x) {
    float e = __expf(2.0f * x);
    return 1.0f - __fdividef(2.0f, e + 1.0f);     // +-1 at saturation
}
__device__ __forceinline__ half2v pack2_rne(float x, float y) {
    half2v r; r.x = (_Float16)x; r.y = (_Float16)y; return r;
}

// ---------------------------------------------------------------------------
// K1a: z[s] = W_exp[pos_ids[s]] @ embs[s] + b_exp  -> xg[s*512 + 0..128)
// ---------------------------------------------------------------------------
__global__ __launch_bounds__(64) void expert_gemv(
    const float* __restrict__ embs, const int* __restrict__ pos_ids,
    const float* __restrict__ W_exp, const float* __restrict__ b_exp,
    float* __restrict__ xg)
{
    __shared__ float Wl[DIM * DIM];          // 64KB, rows XOR-swizzled
    const int e     = blockIdx.x % NEXP;
    const int slice = blockIdx.x / NEXP;     // 0..7
    const int tid   = threadIdx.x;           // 0..63

    const float4* Wg = (const float4*)(W_exp + (size_t)e * DIM * DIM);
    #pragma unroll 4
    for (int it = 0; it < 64; ++it) {
        int idx = it * 64 + tid;             // 0..4095 float4s
        int r = idx >> 5, c4 = idx & 31;
        float4 v = Wg[idx];
        *(float4*)&Wl[r * DIM + (((c4 ^ (r & 31))) << 2)] = v;
    }
    const float b0 = b_exp[e * DIM + tid];
    const float b1 = b_exp[e * DIM + 64 + tid];
    __syncthreads();

    const int r0 = tid, r1 = tid + 64;
    const int sw0 = r0 & 31, sw1 = r1 & 31;
    const int sBeg = slice * 1024, sEnd = sBeg + 1024;
    for (int base = sBeg; base < sEnd; base += 64) {
        int pid = pos_ids[base + tid];
        unsigned long long m = __ballot(pid == e);
        while (m) {
            int t = __builtin_ctzll(m);
            m &= m - 1;
            int s = base + t;
            const float4* ev = (const float4*)(embs + (size_t)s * DIM);
            float a0 = b0, a1 = b1;
            #pragma unroll
            for (int j4 = 0; j4 < 32; ++j4) {
                float4 x  = ev[j4];
                float4 w0 = *(const float4*)&Wl[r0 * DIM + ((j4 ^ sw0) << 2)];
                float4 w1 = *(const float4*)&Wl[r1 * DIM + ((j4 ^ sw1) << 2)];
                a0 = fmaf(w0.x,x.x,fmaf(w0.y,x.y,fmaf(w0.z,x.z,fmaf(w0.w,x.w,a0))));
                a1 = fmaf(w1.x,x.x,fmaf(w1.y,x.y,fmaf(w1.z,x.z,fmaf(w1.w,x.w,a1))));
            }
            float* zp = xg + (size_t)s * NGATE;
            zp[tid]      = a0;
            zp[tid + 64] = a1;
        }
    }
}

// ---------------------------------------------------------------------------
// K1b: xg[s] = W_ih @ z[s] + b_ih + b_hh   (z read from xg[s*512+0..128))
// ---------------------------------------------------------------------------
__global__ __launch_bounds__(256) void gate_gemm(
    const float* __restrict__ W_ih, const float* __restrict__ b_ih,
    const float* __restrict__ b_hh, float* __restrict__ xg)
{
    __shared__ float zl[32 * DIM];    // 16KB
    __shared__ float Wl[64 * DIM];    // 32KB
    const int tid = threadIdx.x;
    const int s0  = blockIdx.x * 32;

    #pragma unroll
    for (int it = 0; it < 4; ++it) {
        int idx = it * 256 + tid;
        int tok = idx >> 5, c4 = idx & 31;
        float4 v = *(const float4*)(xg + ((size_t)(s0 + tok)) * NGATE + (c4 << 2));
        *(float4*)&zl[tok * DIM + (((c4 ^ (tok & 31))) << 2)] = v;
    }
    __syncthreads();

    const int lane = tid & 63;
    const int tg   = tid >> 6;
    const int swr  = lane & 31;

    for (int ch = 0; ch < 8; ++ch) {
        #pragma unroll
        for (int it = 0; it < 8; ++it) {
            int idx = it * 256 + tid;
            int r = idx >> 5, c4 = idx & 31;
            float4 v = *(const float4*)(W_ih + ((size_t)(ch * 64 + r)) * DIM + (c4 << 2));
            *(float4*)&Wl[r * DIM + ((c4 ^ (r & 31)) << 2)] = v;
        }
        __syncthreads();

        const int row = ch * 64 + lane;
        const float bias = b_ih[row] + b_hh[row];
        float acc[8];
        #pragma unroll
        for (int k = 0; k < 8; ++k) acc[k] = bias;
        #pragma unroll 8
        for (int j4 = 0; j4 < 32; ++j4) {
            float4 w = *(const float4*)&Wl[lane * DIM + ((j4 ^ swr) << 2)];
            #pragma unroll
            for (int k = 0; k < 8; ++k) {
                int tok = tg * 8 + k;
                float4 z = *(const float4*)&zl[tok * DIM + ((j4 ^ (tok & 31)) << 2)];
                acc[k] = fmaf(w.x,z.x,fmaf(w.y,z.y,fmaf(w.z,z.z,fmaf(w.w,z.w,acc[k]))));
            }
        }
        #pragma unroll
        for (int k = 0; k < 8; ++k) {
            int tok = tg * 8 + k;
            xg[((size_t)(s0 + tok)) * NGATE + row] = acc[k];
        }
        __syncthreads();
    }
}

// ---------------------------------------------------------------------------
// K2: LSTM scan + max-pool. ONE block, 256 threads (4 waves, 1 wave/SIMD).
// ---------------------------------------------------------------------------
__global__ __launch_bounds__(256, 2) void lstm_scan(
    const float* __restrict__ xg, const float* __restrict__ W_hh,
    float* __restrict__ out)
{
    const int G = threadIdx.x;     // 0..255
    const int L = G & 63;
    const int row0 = G;            // i (0..127) / f (128..255)
    const int row1 = G + 256;      // g (256..383) / o (384..511)

    __shared__ float gbuf[2][NGATE];

    // --- W_hh rows packed to half2, straight-line load (constant indices ->
    //     SROA -> SSA values -> registers; RNE rounding for weights) ---
    half2v wp0[64], wp1[64];
    {
        const float4* r0p = (const float4*)(W_hh + (size_t)row0 * DIM);
        const float4* r1p = (const float4*)(W_hh + (size_t)row1 * DIM);
#define LOADW(k4) { \
        float4 a = r0p[(k4)]; \
        wp0[2*(k4)]   = pack2_rne(a.x, a.y); \
        wp0[2*(k4)+1] = pack2_rne(a.z, a.w); \
        float4 b = r1p[(k4)]; \
        wp1[2*(k4)]   = pack2_rne(b.x, b.y); \
        wp1[2*(k4)+1] = pack2_rne(b.z, b.w); }
        LOADW(0)  LOADW(1)  LOADW(2)  LOADW(3)  LOADW(4)  LOADW(5)  LOADW(6)  LOADW(7)
        LOADW(8)  LOADW(9)  LOADW(10) LOADW(11) LOADW(12) LOADW(13) LOADW(14) LOADW(15)
        LOADW(16) LOADW(17) LOADW(18) LOADW(19) LOADW(20) LOADW(21) LOADW(22) LOADW(23)
        LOADW(24) LOADW(25) LOADW(26) LOADW(27) LOADW(28) LOADW(29) LOADW(30) LOADW(31)
#undef LOADW
    }

    float2 hv  = {0.0f, 0.0f};
    float2 cv  = {0.0f, 0.0f};
    float2 hmx = {-INFINITY, -INFINITY};
    int hp = 0;   // packed half2 (h[2L], h[2L+1]); zero bits == (0,0)

    // scalar (wave-uniform) flag: does this thread's row1 use tanh (g) or sigmoid (o)?
    const bool row1_is_g = (__builtin_amdgcn_readfirstlane(G) < 128);

    // xg pipeline, distance 2
    float x0a = xg[row0],         x1a = xg[row1];
    float x0b = xg[NGATE + row0], x1b = xg[NGATE + row1];

    for (int t = 0; t < SEQ; ++t) {
        const int tn = (t + 2 < SEQ) ? (t + 2) : (SEQ - 1);
        const float x0n = xg[(size_t)tn * NGATE + row0];
        const float x1n = xg[(size_t)tn * NGATE + row1];

        // --- dot(W_hh[row], h): straight-line, constant lanes/indices ---
        float a0a = 0.0f, a0b = 0.0f, a1a = 0.0f, a1b = 0.0f;
#define DOT2(j) { \
        int si0 = __builtin_amdgcn_readlane(hp, (j)); \
        int si1 = __builtin_amdgcn_readlane(hp, (j)+1); \
        half2v s0 = __builtin_bit_cast(half2v, si0); \
        half2v s1 = __builtin_bit_cast(half2v, si1); \
        a0a = __builtin_amdgcn_fdot2(wp0[(j)],   s0, a0a, false); \
        a1a = __builtin_amdgcn_fdot2(wp1[(j)],   s0, a1a, false); \
        a0b = __builtin_amdgcn_fdot2(wp0[(j)+1], s1, a0b, false); \
        a1b = __builtin_amdgcn_fdot2(wp1[(j)+1], s1, a1b, false); }
        DOT2(0)  DOT2(2)  DOT2(4)  DOT2(6)  DOT2(8)  DOT2(10) DOT2(12) DOT2(14)
        DOT2(16) DOT2(18) DOT2(20) DOT2(22) DOT2(24) DOT2(26) DOT2(28) DOT2(30)
        DOT2(32) DOT2(34) DOT2(36) DOT2(38) DOT2(40) DOT2(42) DOT2(44) DOT2(46)
        DOT2(48) DOT2(50) DOT2(52) DOT2(54) DOT2(56) DOT2(58) DOT2(60) DOT2(62)
#undef DOT2
        const float p0 = x0a + (a0a + a0b);
        const float p1 = x1a + (a1a + a1b);

        const float act0 = sigm_fast(p0);                       // i or f
        float act1;
        if (row1_is_g) act1 = tanh_fast(p1);                    // g (scalar branch)
        else           act1 = sigm_fast(p1);                    // o

        float* gb = gbuf[t & 1];
        gb[row0] = act0;
        gb[row1] = act1;
        __syncthreads();   // single barrier per step (double-buffered gbuf)

        const float2 iv = *(const float2*)(gb + 0   + 2 * L);
        const float2 fv = *(const float2*)(gb + 128 + 2 * L);
        const float2 gv = *(const float2*)(gb + 256 + 2 * L);
        const float2 ov = *(const float2*)(gb + 384 + 2 * L);

        cv.x = fmaf(fv.x, cv.x, iv.x * gv.x);
        cv.y = fmaf(fv.y, cv.y, iv.y * gv.y);
        hv.x = ov.x * tanh_fast(cv.x);
        hv.y = ov.y * tanh_fast(cv.y);

        hmx.x = fmaxf(hmx.x, hv.x);
        hmx.y = fmaxf(hmx.y, hv.y);

        // single-instruction RTZ pack of h (error ~2^-12 on |h|<=1: negligible)
        hp = __builtin_bit_cast(int, __builtin_amdgcn_cvt_pkrtz(hv.x, hv.y));

        x0a = x0b; x1a = x1b; x0b = x0n; x1b = x1n;
    }

    if (G < 64) ((float2*)out)[L] = hmx;
}

// ---------------------------------------------------------------------------
extern "C" void kernel_launch(void* const* d_in, const int* in_sizes, int n_in,
                              void* d_out, int out_size, void* d_ws, size_t ws_size,
                              hipStream_t stream)
{
    const float* embs  = (const float*)d_in[0];
    const int*   pos   = (const int*)  d_in[1];
    const float* W_exp = (const float*)d_in[2];
    const float* b_exp = (const float*)d_in[3];
    const float* W_ih  = (const float*)d_in[4];
    const float* W_hh  = (const float*)d_in[5];
    const float* b_ih  = (const float*)d_in[6];
    const float* b_hh  = (const float*)d_in[7];
    float* out = (float*)d_out;
    float* xg  = (float*)d_ws;   // [SEQ][512] fp32 = 16 MB (z in cols 0..127)

    expert_gemv<<<dim3(NEXP * 8), 64, 0, stream>>>(embs, pos, W_exp, b_exp, xg);
    gate_gemm  <<<dim3(256), 256, 0, stream>>>(W_ih, b_ih, b_hh, xg);
    lstm_scan  <<<dim3(1), 256, 0, stream>>>(xg, W_hh, out);
}